// Round 3
// baseline (106.176 us; speedup 1.0000x reference)
//
#include <hip/hip_runtime.h>
#include <math.h>

#define NPERSEG 1024
#define STEP    256
#define NWIN    61
#define SEQ     16384
#define BATCH   1024

typedef float f32x4 __attribute__((ext_vector_type(4)));

// Kernel 1: effective per-position weights, pre-scaled by 1/NWIN.
// wc[s] = (1/61) * sum over windows w covering s of cos(2*pi*freqs[p]),
// p = s - 256*w. ws[s] = same with -sin. Each position has <= 4 windows.
__global__ void welch_weights_kernel(const float* __restrict__ freqs,
                                     float* __restrict__ wc,
                                     float* __restrict__ ws) {
    int s = blockIdx.x * blockDim.x + threadIdx.x;
    if (s >= SEQ) return;
    int p0    = s & (STEP - 1);   // s mod 256
    int wbase = s >> 8;           // s / 256
    float c = 0.f, sn = 0.f;
    #pragma unroll
    for (int k = 0; k < 4; ++k) {
        int w = wbase - k;
        if (w >= 0 && w < NWIN) {
            int p = p0 + STEP * k;          // always < 1024
            float a = 6.2831853071795864769f * freqs[p];
            float sv, cv;
            sincosf(a, &sv, &cv);
            c  += cv;
            sn -= sv;
        }
    }
    wc[s] = c  * (1.0f / NWIN);
    ws[s] = sn * (1.0f / NWIN);
}

// Kernel 2: 512 blocks, each handles TWO rows (weight loads amortized 2x).
// x is loaded non-temporally (streamed once, never reused) so the 128 KiB
// weight tables stay L2-resident instead of being evicted by the x stream.
__global__ __launch_bounds__(256, 2) void welch_dot2_kernel(
        const float* __restrict__ inp,
        const float* __restrict__ wc,
        const float* __restrict__ ws,
        const float* __restrict__ fc_w,
        const float* __restrict__ fc_b,
        float* __restrict__ out) {
    const int r0 = blockIdx.x * 2;
    const int t  = threadIdx.x;

    const f32x4* __restrict__ xa  = (const f32x4*)(inp + (size_t)r0 * SEQ);
    const f32x4* __restrict__ xb  = (const f32x4*)(inp + (size_t)(r0 + 1) * SEQ);
    const f32x4* __restrict__ wc4 = (const f32x4*)wc;
    const f32x4* __restrict__ ws4 = (const f32x4*)ws;

    float sra = 0.f, sia = 0.f, srb = 0.f, sib = 0.f;
    #pragma unroll 4
    for (int i = 0; i < SEQ / 4 / 256; ++i) {   // 16 iters, coalesced
        int j = t + i * 256;
        f32x4 cv = wc4[j];
        f32x4 sv = ws4[j];
        f32x4 a  = __builtin_nontemporal_load(xa + j);
        f32x4 b  = __builtin_nontemporal_load(xb + j);
        sra += a.x * cv.x + a.y * cv.y + a.z * cv.z + a.w * cv.w;
        sia += a.x * sv.x + a.y * sv.y + a.z * sv.z + a.w * sv.w;
        srb += b.x * cv.x + b.y * cv.y + b.z * cv.z + b.w * cv.w;
        sib += b.x * sv.x + b.y * sv.y + b.z * sv.z + b.w * sv.w;
    }

    // wave64 butterfly reduce (4 accumulators)
    #pragma unroll
    for (int off = 32; off > 0; off >>= 1) {
        sra += __shfl_down(sra, off, 64);
        sia += __shfl_down(sia, off, 64);
        srb += __shfl_down(srb, off, 64);
        sib += __shfl_down(sib, off, 64);
    }

    __shared__ float red[4][4];
    int wave = t >> 6;
    int lane = t & 63;
    if (lane == 0) {
        red[wave][0] = sra; red[wave][1] = sia;
        red[wave][2] = srb; red[wave][3] = sib;
    }
    __syncthreads();

    if (t == 0) {
        float fra = 0.f, fia = 0.f, frb = 0.f, fib = 0.f;
        #pragma unroll
        for (int w = 0; w < 4; ++w) {
            fra += red[w][0]; fia += red[w][1];
            frb += red[w][2]; fib += red[w][3];
        }
        float fw = fc_w[0], fb = fc_b[0];
        out[r0]     = (fra * fra + fia * fia) * fw + fb;   // 1/61 folded into weights
        out[r0 + 1] = (frb * frb + fib * fib) * fw + fb;
    }
}

extern "C" void kernel_launch(void* const* d_in, const int* in_sizes, int n_in,
                              void* d_out, int out_size, void* d_ws, size_t ws_size,
                              hipStream_t stream) {
    const float* inp   = (const float*)d_in[0];   // (1024, 16384) f32
    const float* freqs = (const float*)d_in[1];   // (1024,) f32
    const float* fc_w  = (const float*)d_in[2];   // (1,1) f32
    const float* fc_b  = (const float*)d_in[3];   // (1,) f32
    float* out = (float*)d_out;                   // (1024, 1) f32

    float* wc = (float*)d_ws;                     // 16384 floats
    float* ws = wc + SEQ;                         // 16384 floats (128 KiB total)

    welch_weights_kernel<<<SEQ / 256, 256, 0, stream>>>(freqs, wc, ws);
    welch_dot2_kernel<<<BATCH / 2, 256, 0, stream>>>(inp, wc, ws, fc_w, fc_b, out);
}

// Round 4
// 98.800 us; speedup vs baseline: 1.0746x; 1.0746x over previous
//
#include <hip/hip_runtime.h>
#include <math.h>

#define NPERSEG 1024
#define STEP    256
#define NWIN    61
#define SEQ     16384
#define BATCH   1024

typedef float f32x4 __attribute__((ext_vector_type(4)));

// Fully fused. Algebra: out[b] = (fr^2 + fi^2)*fc_w + fc_b where
//   fr = (1/61) * sum_s x[b,s] * wc[s],  wc[s] = sum_{k in valid(s)} cos(2*pi*freqs[(s mod 256) + 256k])
// and valid(s) = {k in [0,3] : 0 <= (s>>8)-k <= 60}. Thread t handles the
// float4s at j = t + 256*i, so element e always has p0 = (4t+e) mod 256 and
// q = (4t+e)>>8; across iterations only the window-clamp changes:
//   i = 0      -> prefix sum  k = 0..q
//   i = 1..14  -> full sum    k = 0..3
//   i = 15     -> suffix sum  k = q..3
// So 6 weight scalars per element (x cos/sin) live in registers; the inner
// loop is a pure 64 MB stream with 2 FMAs/element. No d_ws, single launch.
__global__ __launch_bounds__(256, 4) void welch_fused_kernel(
        const float* __restrict__ inp,
        const float* __restrict__ freqs,
        const float* __restrict__ fc_w,
        const float* __restrict__ fc_b,
        float* __restrict__ out) {
    const int row = blockIdx.x;
    const int t   = threadIdx.x;

    // Prologue: 16 sincosf per thread -> register weight tables.
    float Fc[4], Fs[4], Pc[4], Ps[4], Sc[4], Ss[4];
    #pragma unroll
    for (int e = 0; e < 4; ++e) {
        int idx = 4 * t + e;          // 0..1023
        int p0  = idx & 255;
        int q   = idx >> 8;           // 0..3
        float fc_ = 0.f, fs_ = 0.f, pc_ = 0.f, ps_ = 0.f, sc_ = 0.f, ss_ = 0.f;
        #pragma unroll
        for (int k = 0; k < 4; ++k) {
            float a = 6.2831853071795864769f * freqs[p0 + 256 * k];
            float sv, cv;
            sincosf(a, &sv, &cv);
            cv *= (1.0f / NWIN);
            sv *= -(1.0f / NWIN);     // reference uses -sin
            fc_ += cv; fs_ += sv;
            if (k <= q) { pc_ += cv; ps_ += sv; }
            if (k >= q) { sc_ += cv; ss_ += sv; }
        }
        Fc[e] = fc_; Fs[e] = fs_;
        Pc[e] = pc_; Ps[e] = ps_;
        Sc[e] = sc_; Ss[e] = ss_;
    }

    const f32x4* __restrict__ x4 = (const f32x4*)(inp + (size_t)row * SEQ);

    float sr = 0.f, si = 0.f;
    {   // i = 0: prefix weights
        f32x4 x = x4[t];
        sr += x.x * Pc[0] + x.y * Pc[1] + x.z * Pc[2] + x.w * Pc[3];
        si += x.x * Ps[0] + x.y * Ps[1] + x.z * Ps[2] + x.w * Ps[3];
    }
    #pragma unroll 7
    for (int i = 1; i < 15; ++i) {    // bulk: full-sum weights
        f32x4 x = x4[t + 256 * i];
        sr += x.x * Fc[0] + x.y * Fc[1] + x.z * Fc[2] + x.w * Fc[3];
        si += x.x * Fs[0] + x.y * Fs[1] + x.z * Fs[2] + x.w * Fs[3];
    }
    {   // i = 15: suffix weights
        f32x4 x = x4[t + 256 * 15];
        sr += x.x * Sc[0] + x.y * Sc[1] + x.z * Sc[2] + x.w * Sc[3];
        si += x.x * Ss[0] + x.y * Ss[1] + x.z * Ss[2] + x.w * Ss[3];
    }

    // wave64 butterfly reduce
    #pragma unroll
    for (int off = 32; off > 0; off >>= 1) {
        sr += __shfl_down(sr, off, 64);
        si += __shfl_down(si, off, 64);
    }

    __shared__ float red[4][2];
    int wave = t >> 6;
    int lane = t & 63;
    if (lane == 0) { red[wave][0] = sr; red[wave][1] = si; }
    __syncthreads();

    if (t == 0) {
        float fr = red[0][0] + red[1][0] + red[2][0] + red[3][0];
        float fi = red[0][1] + red[1][1] + red[2][1] + red[3][1];
        out[row] = (fr * fr + fi * fi) * fc_w[0] + fc_b[0];
    }
}

extern "C" void kernel_launch(void* const* d_in, const int* in_sizes, int n_in,
                              void* d_out, int out_size, void* d_ws, size_t ws_size,
                              hipStream_t stream) {
    const float* inp   = (const float*)d_in[0];   // (1024, 16384) f32
    const float* freqs = (const float*)d_in[1];   // (1024,) f32
    const float* fc_w  = (const float*)d_in[2];   // (1,1) f32
    const float* fc_b  = (const float*)d_in[3];   // (1,) f32
    float* out = (float*)d_out;                   // (1024, 1) f32

    welch_fused_kernel<<<BATCH, 256, 0, stream>>>(inp, freqs, fc_w, fc_b, out);
}